// Round 10
// baseline (329.960 us; speedup 1.0000x reference)
//
#include <hip/hip_runtime.h>
#include <cstddef>
#include <math.h>

static constexpr int L = 1024;
static constexpr int B = 4;
static constexpr int NSTEPS = 16;   // setup_inputs() always passes steps=16
static constexpr int NTILE = 16;
static constexpr int NPAIR = NTILE * (NTILE + 1) / 2;  // 136
static constexpr int BL = B * L;

// ws layout (float offsets). Everything is write-before-read (ws poisoned 0xAA).
static constexpr size_t AH_OFF  = 0;                               // fp32 B*L*L
static constexpr size_t US_OFF  = (size_t)B * L * L;               // fp32 B*L*L
static constexpr size_t RP_OFF  = 2 * (size_t)B * L * L;           // fp32 B*16*L row partials
static constexpr size_t CP_OFF  = RP_OFF + (size_t)B * 16 * L;     // fp32 B*16*L col partials
static constexpr size_t LM_OFF  = CP_OFF + (size_t)B * 16 * L;     // fp32 B*L
static constexpr size_t CC_OFF  = LM_OFF + (size_t)BL;             // fp32 B*L
static constexpr size_t SC_OFF  = CC_OFF + (size_t)BL;             // 64 floats

// ---------------------------------------------------------------------------
// R10 note: R9's tile-pair update regressed (12.6us/step) because pass-2
// loads serialized behind pass-1 compute+store+barrier. R10 keeps the byte
// diet (us symmetric -> mirror tile from LDS) but issues ALL five tile loads
// (ah1,us1,rho1,ah2,rho2) upfront — one deep independent load burst, then
// ALU-only compute. us1 is stored PRE-TRANSPOSED to LDS (4B scatter stores,
// 2-way bank aliasing = free) so pass 2 reads contiguous float4. Two cpw
// buffers avoid R9's extra sync. Everything else is the R8-proven structure.
// ---------------------------------------------------------------------------

// init: ah = x*M, us = 0.5*(x+x^T)-s (both fp32 — fp16 fails: sign(row)*Lm
// with Lm~O(100) amplifies 1e-4 input noise, prior-session post-mortem),
// plus fused step-0 16-way tile partial row/col sums. One 64x64 tile per
// block. XCD swizzle: bid%8 = row-chunk.
__global__ __launch_bounds__(256) void init_kernel(
    const float* __restrict__ x, const float* __restrict__ M,
    const float* __restrict__ sp,
    float* __restrict__ ah, float* __restrict__ us,
    float* __restrict__ Rpart, float* __restrict__ Cpart)
{
    __shared__ float lt[64][65];
    __shared__ float cpw[4][64];
    const int bid  = blockIdx.x;
    const int chunk = bid & 7;            // row-chunk -> XCD (round-robin)
    const int rest  = bid >> 3;           // 0..127
    const int b  = rest >> 5;             // 0..3
    const int ti = (chunk << 1) | ((rest >> 4) & 1);
    const int tj = rest & 15;
    const int t  = threadIdx.x;
    const int w  = t >> 6;
    const int r  = t >> 4;            // 0..15
    const int c4 = (t & 15) << 2;
    const float s = sp[0];
    const float* xb = x + (size_t)b * L * L;

#pragma unroll
    for (int it = 0; it < 4; ++it) {
        int rr = r + 16 * it;
        float4 v = *(const float4*)(xb + (size_t)(tj * 64 + rr) * L + ti * 64 + c4);
        lt[rr][c4+0] = v.x; lt[rr][c4+1] = v.y; lt[rr][c4+2] = v.z; lt[rr][c4+3] = v.w;
    }
    __syncthreads();

    float cs0 = 0.f, cs1 = 0.f, cs2 = 0.f, cs3 = 0.f;
#pragma unroll
    for (int it = 0; it < 4; ++it) {
        int rr = r + 16 * it;
        int gi = ti * 64 + rr;
        size_t off = (size_t)b * L * L + (size_t)gi * L + tj * 64 + c4;
        float4 xv = *(const float4*)(x + off);
        float4 mv = *(const float4*)(M + off);
        *(float4*)(us + off) = make_float4(0.5f*(xv.x + lt[c4+0][rr]) - s,
                                           0.5f*(xv.y + lt[c4+1][rr]) - s,
                                           0.5f*(xv.z + lt[c4+2][rr]) - s,
                                           0.5f*(xv.w + lt[c4+3][rr]) - s);
        float a0 = xv.x*mv.x, a1 = xv.y*mv.y, a2 = xv.z*mv.z, a3 = xv.w*mv.w;
        *(float4*)(ah + off) = make_float4(a0, a1, a2, a3);
        // tile row partial (16 lanes share row rr)
        float rs = (a0 + a1) + (a2 + a3);
        rs += __shfl_xor(rs, 1); rs += __shfl_xor(rs, 2);
        rs += __shfl_xor(rs, 4); rs += __shfl_xor(rs, 8);
        if ((t & 15) == 0) Rpart[((size_t)(b * 16 + tj)) * L + gi] = rs;
        cs0 += a0; cs1 += a1; cs2 += a2; cs3 += a3;
    }
    // tile col partial: reduce over the wave's 4 r-values (lane xor 16, 32)
    cs0 += __shfl_xor(cs0, 16); cs0 += __shfl_xor(cs0, 32);
    cs1 += __shfl_xor(cs1, 16); cs1 += __shfl_xor(cs1, 32);
    cs2 += __shfl_xor(cs2, 16); cs2 += __shfl_xor(cs2, 32);
    cs3 += __shfl_xor(cs3, 16); cs3 += __shfl_xor(cs3, 32);
    if ((t & 63) < 16) {
        int c0 = (t & 63) << 2;
        cpw[w][c0+0] = cs0; cpw[w][c0+1] = cs1; cpw[w][c0+2] = cs2; cpw[w][c0+3] = cs3;
    }
    __syncthreads();
    if (t < 64)
        Cpart[((size_t)(b * 16 + ti)) * L + tj * 64 + t] =
            (cpw[0][t] + cpw[1][t]) + (cpw[2][t] + cpw[3][t]);
}

// ---------------------------------------------------------------------------
// lminit (+prep fused): block 0 also fills the per-step scalar table sc.
// ---------------------------------------------------------------------------
__global__ __launch_bounds__(256) void lminit_kernel(
    const float* __restrict__ wp,
    const float* __restrict__ alphap, const float* __restrict__ beltp,
    const float* __restrict__ lrap,  const float* __restrict__ lrbp,
    const float* __restrict__ Rpart, const float* __restrict__ Cpart,
    float* __restrict__ Lm, float* __restrict__ cc, float* __restrict__ sc)
{
    const int bid = blockIdx.x;
    const int t   = threadIdx.x;
    if (bid == 0 && t < NSTEPS) {
        sc[t]          = alphap[0] * powf(lrap[0], (float)t);
        sc[NSTEPS + t] = beltp[0]  * powf(lrbp[0], (float)t);
    }
    const int b   = bid >> 2;
    const int i   = ((bid & 3) << 8) + t;
    float R0 = 0.f, C0 = 0.f;
#pragma unroll
    for (int k = 0; k < 16; ++k) {
        R0 += Rpart[((size_t)(b * 16 + k)) * L + i];
        C0 += Cpart[((size_t)(b * 16 + k)) * L + i];
    }
    float rowv = 0.5f * (R0 + C0) - 1.0f;
    float rl = fmaxf(rowv, 0.f);
    float lm = wp[0] * rl;
    Lm[b * L + i] = lm;
    float sg = (rowv > 0.f) ? 1.f : ((rowv < 0.f) ? -1.f : 0.f);
    cc[b * L + i] = lm * sg;
}

__device__ __forceinline__ float step_elem(float a, float u, float rho,
                                           float ci, float cj, float at) {
    float g = u - ci - cj;
    float v = a * (1.f + at * g);
    v = fmaxf(fabsf(v) - rho * at, 0.f);
    return fminf(v, 1.f);
}

__device__ __forceinline__ void decode_pair(int p, int& ti, int& tj) {
    int t = 0;
    while (p >= NTILE - t) { p -= NTILE - t; ++t; }
    ti = t; tj = t + p;
}

// ---------------------------------------------------------------------------
// updpair (v2): one step for tile pair (ti,tj)+(tj,ti), 512 threads.
// ALL global tile loads issued upfront (ah1,us1,rho1,ah2,rho2 — independent,
// one deep burst); us1 stored pre-transposed to LDS so pass 2 reads float4.
// Partials in init format (unique writer per (chunk,partial) as in R9 —
// verified correct there). Task->tile mapping fixed across dispatches ->
// same XCD L2 serves the same tiles every step.
// ---------------------------------------------------------------------------
__global__ __launch_bounds__(512) void updpair_kernel(
    const float* __restrict__ rho, const float* __restrict__ sc,
    float* __restrict__ ah, const float* __restrict__ us,
    const float* __restrict__ cc,
    float* __restrict__ Rpart, float* __restrict__ Cpart, int p)
{
    __shared__ float ut[64][65];      // us tile 1, TRANSPOSED at store time
    __shared__ float cpwA[8][64];
    __shared__ float cpwB[8][64];
    const int task = blockIdx.x;
    const int b = task / NPAIR;
    int ti, tj; decode_pair(task % NPAIR, ti, tj);
    const int t  = threadIdx.x;       // 0..511
    const int w  = t >> 6;            // 0..7
    const int r0 = t >> 4;            // 0..31
    const int c4 = (t & 15) << 2;
    const bool diag = (ti == tj);
    const float at = sc[p];
    const float* ccb = cc + b * L;
    const size_t bb = (size_t)b * L * L;

    // ---- load burst: everything upfront, fully independent ----
    float4 av1[2], uv1[2], hv1[2], av2[2], hv2[2];
#pragma unroll
    for (int it = 0; it < 2; ++it) {
        const int r  = r0 + 32 * it;
        const size_t o1 = (size_t)(ti * 64 + r) * L + tj * 64 + c4;
        av1[it] = *(const float4*)(ah + bb + o1);
        uv1[it] = *(const float4*)(us + bb + o1);
        hv1[it] = *(const float4*)(rho + o1);
    }
    if (!diag) {
#pragma unroll
        for (int it = 0; it < 2; ++it) {
            const int r  = r0 + 32 * it;
            const size_t o2 = (size_t)(tj * 64 + r) * L + ti * 64 + c4;
            av2[it] = *(const float4*)(ah + bb + o2);
            hv2[it] = *(const float4*)(rho + o2);
        }
    }
    // stage us1 transposed: ut[col][row] (4B scatter, 2-way bank alias = free)
#pragma unroll
    for (int it = 0; it < 2; ++it) {
        const int r = r0 + 32 * it;
        ut[c4+0][r] = uv1[it].x; ut[c4+1][r] = uv1[it].y;
        ut[c4+2][r] = uv1[it].z; ut[c4+3][r] = uv1[it].w;
    }
    __syncthreads();

    // ---- pass 1: tile (ti,tj) ----
    {
        float4 cjv = *(const float4*)(ccb + tj * 64 + c4);
        float cs0 = 0.f, cs1 = 0.f, cs2 = 0.f, cs3 = 0.f;
#pragma unroll
        for (int it = 0; it < 2; ++it) {
            const int r  = r0 + 32 * it;
            const int gi = ti * 64 + r;
            const float ci = ccb[gi];
            float n0 = step_elem(av1[it].x, uv1[it].x, hv1[it].x, ci, cjv.x, at);
            float n1 = step_elem(av1[it].y, uv1[it].y, hv1[it].y, ci, cjv.y, at);
            float n2 = step_elem(av1[it].z, uv1[it].z, hv1[it].z, ci, cjv.z, at);
            float n3 = step_elem(av1[it].w, uv1[it].w, hv1[it].w, ci, cjv.w, at);
            *(float4*)(ah + bb + (size_t)gi * L + tj * 64 + c4) =
                make_float4(n0, n1, n2, n3);
            float rs = (n0 + n1) + (n2 + n3);
            rs += __shfl_xor(rs, 1); rs += __shfl_xor(rs, 2);
            rs += __shfl_xor(rs, 4); rs += __shfl_xor(rs, 8);
            if ((t & 15) == 0) Rpart[((size_t)(b * 16 + tj)) * L + gi] = rs;
            cs0 += n0; cs1 += n1; cs2 += n2; cs3 += n3;
        }
        cs0 += __shfl_xor(cs0, 16); cs0 += __shfl_xor(cs0, 32);
        cs1 += __shfl_xor(cs1, 16); cs1 += __shfl_xor(cs1, 32);
        cs2 += __shfl_xor(cs2, 16); cs2 += __shfl_xor(cs2, 32);
        cs3 += __shfl_xor(cs3, 16); cs3 += __shfl_xor(cs3, 32);
        if ((t & 63) < 16) {
            int c0 = (t & 63) << 2;
            cpwA[w][c0+0] = cs0; cpwA[w][c0+1] = cs1;
            cpwA[w][c0+2] = cs2; cpwA[w][c0+3] = cs3;
        }
    }

    // ---- pass 2: mirror tile (tj,ti); us from pre-transposed LDS ----
    if (!diag) {
        float4 cjv = *(const float4*)(ccb + ti * 64 + c4);
        float cs0 = 0.f, cs1 = 0.f, cs2 = 0.f, cs3 = 0.f;
#pragma unroll
        for (int it = 0; it < 2; ++it) {
            const int r  = r0 + 32 * it;
            const int gi = tj * 64 + r;
            const float ci = ccb[gi];
            const float* urow = &ut[r][c4];   // contiguous float4 read
            float n0 = step_elem(av2[it].x, urow[0], hv2[it].x, ci, cjv.x, at);
            float n1 = step_elem(av2[it].y, urow[1], hv2[it].y, ci, cjv.y, at);
            float n2 = step_elem(av2[it].z, urow[2], hv2[it].z, ci, cjv.z, at);
            float n3 = step_elem(av2[it].w, urow[3], hv2[it].w, ci, cjv.w, at);
            *(float4*)(ah + bb + (size_t)gi * L + ti * 64 + c4) =
                make_float4(n0, n1, n2, n3);
            float rs = (n0 + n1) + (n2 + n3);
            rs += __shfl_xor(rs, 1); rs += __shfl_xor(rs, 2);
            rs += __shfl_xor(rs, 4); rs += __shfl_xor(rs, 8);
            if ((t & 15) == 0) Rpart[((size_t)(b * 16 + ti)) * L + gi] = rs;
            cs0 += n0; cs1 += n1; cs2 += n2; cs3 += n3;
        }
        cs0 += __shfl_xor(cs0, 16); cs0 += __shfl_xor(cs0, 32);
        cs1 += __shfl_xor(cs1, 16); cs1 += __shfl_xor(cs1, 32);
        cs2 += __shfl_xor(cs2, 16); cs2 += __shfl_xor(cs2, 32);
        cs3 += __shfl_xor(cs3, 16); cs3 += __shfl_xor(cs3, 32);
        if ((t & 63) < 16) {
            int c0 = (t & 63) << 2;
            cpwB[w][c0+0] = cs0; cpwB[w][c0+1] = cs1;
            cpwB[w][c0+2] = cs2; cpwB[w][c0+3] = cs3;
        }
    }
    __syncthreads();

    if (t < 64) {
        float tot = 0.f;
#pragma unroll
        for (int j = 0; j < 8; ++j) tot += cpwA[j][t];
        Cpart[((size_t)(b * 16 + ti)) * L + tj * 64 + t] = tot;
    } else if (t >= 64 && t < 128 && !diag) {
        const int l = t - 64;
        float tot = 0.f;
#pragma unroll
        for (int j = 0; j < 8; ++j) tot += cpwB[j][l];
        Cpart[((size_t)(b * 16 + tj)) * L + ti * 64 + l] = tot;
    }
}

// ---------------------------------------------------------------------------
// lmreduce: lminit-shaped (16 blocks x 256): sum the 16-way tile partials,
// update Lm, write cc for the next dispatch.
// ---------------------------------------------------------------------------
__global__ __launch_bounds__(256) void lmreduce_kernel(
    const float* __restrict__ sc,
    const float* __restrict__ Rpart, const float* __restrict__ Cpart,
    float* __restrict__ Lm, float* __restrict__ cc, int p)
{
    const int bid = blockIdx.x;
    const int t   = threadIdx.x;
    const int b   = bid >> 2;
    const int i   = ((bid & 3) << 8) + t;
    float R0 = 0.f, C0 = 0.f;
#pragma unroll
    for (int k = 0; k < 16; ++k) {
        R0 += Rpart[((size_t)(b * 16 + k)) * L + i];
        C0 += Cpart[((size_t)(b * 16 + k)) * L + i];
    }
    float rowv = 0.5f * (R0 + C0) - 1.0f;
    float lm = Lm[b * L + i] + sc[NSTEPS + p] * fmaxf(rowv, 0.f);
    Lm[b * L + i] = lm;
    float sg = (rowv > 0.f) ? 1.f : ((rowv < 0.f) ? -1.f : 0.f);
    cc[b * L + i] = lm * sg;
}

// ---------------------------------------------------------------------------
// updfinal: step-15 update FUSED with symmetrize-output (verified R6-R9).
// Tile-pair per block; us symmetric — read once, transpose via LDS; ah never
// written back. cc comes from lmreduce(14).
// ---------------------------------------------------------------------------
__global__ __launch_bounds__(256) void updfinal_kernel(
    const float* __restrict__ rho, const float* __restrict__ sc,
    const float* __restrict__ ah, const float* __restrict__ us,
    const float* __restrict__ cc, float* __restrict__ out)
{
    __shared__ float la[64][65];
    __shared__ float lb[64][65];
    __shared__ float uu[64][65];
    const int task = blockIdx.x;
    const int b = task / NPAIR;
    int ti, tj; decode_pair(task % NPAIR, ti, tj);
    const int t  = threadIdx.x;
    const int r0 = t >> 4;
    const int c0 = (t & 15) << 2;
    const float at = sc[NSTEPS - 1];
    const float* ccb = cc + b * L;
    const float* ahb = ah  + (size_t)b * L * L;
    const float* usb = us  + (size_t)b * L * L;
    float* ob        = out + (size_t)b * L * L;

    // pass 1: (ti,tj) tile — direct orientation
    {
        float4 cjv = *(const float4*)(ccb + tj * 64 + c0);
        for (int it = 0; it < 4; ++it) {
            int r = r0 + 16 * it;
            int gi = ti * 64 + r;
            size_t off = (size_t)gi * L + tj * 64 + c0;
            float4 av = *(const float4*)(ahb + off);
            float4 uv = *(const float4*)(usb + off);
            float4 hv = *(const float4*)(rho + off);
            float ci = ccb[gi];
            la[r][c0+0] = step_elem(av.x, uv.x, hv.x, ci, cjv.x, at);
            la[r][c0+1] = step_elem(av.y, uv.y, hv.y, ci, cjv.y, at);
            la[r][c0+2] = step_elem(av.z, uv.z, hv.z, ci, cjv.z, at);
            la[r][c0+3] = step_elem(av.w, uv.w, hv.w, ci, cjv.w, at);
            uu[r][c0+0] = uv.x; uu[r][c0+1] = uv.y;
            uu[r][c0+2] = uv.z; uu[r][c0+3] = uv.w;
        }
    }
    __syncthreads();
    // pass 2: (tj,ti) tile — us from transposed LDS (us symmetric)
    if (ti != tj) {
        float4 cjv = *(const float4*)(ccb + ti * 64 + c0);
        for (int it = 0; it < 4; ++it) {
            int r = r0 + 16 * it;
            int gi = tj * 64 + r;
            size_t off = (size_t)gi * L + ti * 64 + c0;
            float4 av = *(const float4*)(ahb + off);
            float4 hv = *(const float4*)(rho + off);
            float ci = ccb[gi];
            lb[r][c0+0] = step_elem(av.x, uu[c0+0][r], hv.x, ci, cjv.x, at);
            lb[r][c0+1] = step_elem(av.y, uu[c0+1][r], hv.y, ci, cjv.y, at);
            lb[r][c0+2] = step_elem(av.z, uu[c0+2][r], hv.z, ci, cjv.z, at);
            lb[r][c0+3] = step_elem(av.w, uu[c0+3][r], hv.w, ci, cjv.w, at);
        }
    }
    __syncthreads();

    for (int it = 0; it < 4; ++it) {
        int r = r0 + 16 * it;
        size_t off = (size_t)(ti * 64 + r) * L + tj * 64 + c0;
        float tb0, tb1, tb2, tb3;
        if (ti == tj) { tb0 = la[c0+0][r]; tb1 = la[c0+1][r]; tb2 = la[c0+2][r]; tb3 = la[c0+3][r]; }
        else          { tb0 = lb[c0+0][r]; tb1 = lb[c0+1][r]; tb2 = lb[c0+2][r]; tb3 = lb[c0+3][r]; }
        *(float4*)(ob + off) = make_float4(0.5f*(la[r][c0+0]+tb0), 0.5f*(la[r][c0+1]+tb1),
                                           0.5f*(la[r][c0+2]+tb2), 0.5f*(la[r][c0+3]+tb3));
    }
    if (ti != tj) {
        for (int it = 0; it < 4; ++it) {
            int r = r0 + 16 * it;
            size_t off = (size_t)(tj * 64 + r) * L + ti * 64 + c0;
            *(float4*)(ob + off) = make_float4(0.5f*(lb[r][c0+0]+la[c0+0][r]),
                                               0.5f*(lb[r][c0+1]+la[c0+1][r]),
                                               0.5f*(lb[r][c0+2]+la[c0+2][r]),
                                               0.5f*(lb[r][c0+3]+la[c0+3][r]));
        }
    }
}

extern "C" void kernel_launch(void* const* d_in, const int* in_sizes, int n_in,
                              void* d_out, int out_size, void* d_ws, size_t ws_size,
                              hipStream_t stream) {
    const float* x     = (const float*)d_in[0];
    const float* M     = (const float*)d_in[1];
    const float* s     = (const float*)d_in[2];
    const float* w     = (const float*)d_in[3];
    const float* rho   = (const float*)d_in[4];
    const float* alpha = (const float*)d_in[5];
    const float* belt  = (const float*)d_in[6];
    const float* lra   = (const float*)d_in[7];
    const float* lrb   = (const float*)d_in[8];
    float* out = (float*)d_out;

    float* ws     = (float*)d_ws;
    float* ah     = ws + AH_OFF;
    float* us     = ws + US_OFF;
    float* Rpart  = ws + RP_OFF;
    float* Cpart  = ws + CP_OFF;
    float* Lm     = ws + LM_OFF;
    float* cc     = ws + CC_OFF;
    float* sc     = ws + SC_OFF;

    init_kernel<<<dim3(1024), dim3(256), 0, stream>>>(x, M, s, ah, us, Rpart, Cpart);
    lminit_kernel<<<dim3(16), dim3(256), 0, stream>>>(
        w, alpha, belt, lra, lrb, Rpart, Cpart, Lm, cc, sc);
    for (int p = 0; p < NSTEPS - 1; ++p) {
        updpair_kernel<<<dim3(B * NPAIR), dim3(512), 0, stream>>>(
            rho, sc, ah, us, cc, Rpart, Cpart, p);
        lmreduce_kernel<<<dim3(16), dim3(256), 0, stream>>>(
            sc, Rpart, Cpart, Lm, cc, p);
    }
    // step 15 fused with symmetrize-output: reads cc from lmreduce(14)
    updfinal_kernel<<<dim3(B * NPAIR), dim3(256), 0, stream>>>(
        rho, sc, ah, us, cc, out);
}

// Round 11
// 272.590 us; speedup vs baseline: 1.2105x; 1.2105x over previous
//
#include <hip/hip_runtime.h>
#include <cstddef>
#include <math.h>

static constexpr int L = 1024;
static constexpr int B = 4;
static constexpr int NSTEPS = 16;   // setup_inputs() always passes steps=16
static constexpr int NTILE = 16;
static constexpr int NPAIR = NTILE * (NTILE + 1) / 2;  // 136

// ws layout (float offsets). Everything is write-before-read (ws poisoned 0xAA).
static constexpr size_t AH_OFF  = 0;                               // fp32 B*L*L
static constexpr size_t US_OFF  = (size_t)B * L * L;               // fp32 B*L*L
static constexpr size_t CP_OFF  = 2 * (size_t)B * L * L;           // fp32 (region sized B*256*L, half used)
static constexpr size_t RP0_OFF = CP_OFF + (size_t)B * 256 * L;    // fp32 B*16*L
static constexpr size_t CP0_OFF = RP0_OFF + (size_t)B * 16 * L;    // fp32 B*16*L
static constexpr size_t R_OFF   = CP0_OFF + (size_t)B * 16 * L;    // fp32 B*L
static constexpr size_t LM_OFF  = R_OFF + (size_t)B * L;
static constexpr size_t CC_OFF  = LM_OFF + (size_t)B * L;
static constexpr size_t SC_OFF  = CC_OFF + (size_t)B * L;          // 64 floats

// ---------------------------------------------------------------------------
// R11 note (final structure): R1-R7 measured every in-kernel cross-block
// exchange (cooperative persistent kernel, flat/tree/per-batch barriers,
// banked u64 atomics, producer-side and consumer-side reducer folds) — all
// lose to the plain in-order dispatch boundary (~4us). R9/R10 measured the
// us-symmetry byte diet (tile-pair update, serialized and burst-load forms)
// — both lose to the row-slab's contiguous streaming. The row-slab update
// (10us for the mandatory 67MB/step = 16B/element) is within ~10% of the
// element-parallel streaming minimum on this cache hierarchy. This file is
// the measured optimum: R0 loop + last-step/symmetrize fusion (275us, R8).
// ---------------------------------------------------------------------------

// init: ah = x*M, us = 0.5*(x+x^T)-s (both fp32 — fp16 fails: sign(row)*Lm
// with Lm~O(100) amplifies 1e-4 input noise, prior-session post-mortem),
// plus fused step-0 16-way tile partial row/col sums. One 64x64 tile per
// block. XCD swizzle: bid%8 = row-chunk.
__global__ __launch_bounds__(256) void init_kernel(
    const float* __restrict__ x, const float* __restrict__ M,
    const float* __restrict__ sp,
    float* __restrict__ ah, float* __restrict__ us,
    float* __restrict__ Rpart, float* __restrict__ Cpart0)
{
    __shared__ float lt[64][65];
    __shared__ float cpw[4][64];
    const int bid  = blockIdx.x;
    const int chunk = bid & 7;            // row-chunk -> XCD (round-robin)
    const int rest  = bid >> 3;           // 0..127
    const int b  = rest >> 5;             // 0..3
    const int ti = (chunk << 1) | ((rest >> 4) & 1);
    const int tj = rest & 15;
    const int t  = threadIdx.x;
    const int w  = t >> 6;
    const int r  = t >> 4;            // 0..15
    const int c4 = (t & 15) << 2;
    const float s = sp[0];
    const float* xb = x + (size_t)b * L * L;

#pragma unroll
    for (int it = 0; it < 4; ++it) {
        int rr = r + 16 * it;
        float4 v = *(const float4*)(xb + (size_t)(tj * 64 + rr) * L + ti * 64 + c4);
        lt[rr][c4+0] = v.x; lt[rr][c4+1] = v.y; lt[rr][c4+2] = v.z; lt[rr][c4+3] = v.w;
    }
    __syncthreads();

    float cs0 = 0.f, cs1 = 0.f, cs2 = 0.f, cs3 = 0.f;
#pragma unroll
    for (int it = 0; it < 4; ++it) {
        int rr = r + 16 * it;
        int gi = ti * 64 + rr;
        size_t off = (size_t)b * L * L + (size_t)gi * L + tj * 64 + c4;
        float4 xv = *(const float4*)(x + off);
        float4 mv = *(const float4*)(M + off);
        *(float4*)(us + off) = make_float4(0.5f*(xv.x + lt[c4+0][rr]) - s,
                                           0.5f*(xv.y + lt[c4+1][rr]) - s,
                                           0.5f*(xv.z + lt[c4+2][rr]) - s,
                                           0.5f*(xv.w + lt[c4+3][rr]) - s);
        float a0 = xv.x*mv.x, a1 = xv.y*mv.y, a2 = xv.z*mv.z, a3 = xv.w*mv.w;
        *(float4*)(ah + off) = make_float4(a0, a1, a2, a3);
        // tile row partial (16 lanes share row rr)
        float rs = (a0 + a1) + (a2 + a3);
        rs += __shfl_xor(rs, 1); rs += __shfl_xor(rs, 2);
        rs += __shfl_xor(rs, 4); rs += __shfl_xor(rs, 8);
        if ((t & 15) == 0) Rpart[((size_t)(b * 16 + tj)) * L + gi] = rs;
        cs0 += a0; cs1 += a1; cs2 += a2; cs3 += a3;
    }
    // tile col partial: reduce over the wave's 4 r-values (lane xor 16, 32)
    cs0 += __shfl_xor(cs0, 16); cs0 += __shfl_xor(cs0, 32);
    cs1 += __shfl_xor(cs1, 16); cs1 += __shfl_xor(cs1, 32);
    cs2 += __shfl_xor(cs2, 16); cs2 += __shfl_xor(cs2, 32);
    cs3 += __shfl_xor(cs3, 16); cs3 += __shfl_xor(cs3, 32);
    if ((t & 63) < 16) {
        int c0 = (t & 63) << 2;
        cpw[w][c0+0] = cs0; cpw[w][c0+1] = cs1; cpw[w][c0+2] = cs2; cpw[w][c0+3] = cs3;
    }
    __syncthreads();
    if (t < 64)
        Cpart0[((size_t)(b * 16 + ti)) * L + tj * 64 + t] =
            (cpw[0][t] + cpw[1][t]) + (cpw[2][t] + cpw[3][t]);
}

// ---------------------------------------------------------------------------
// lminit (+prep fused): block 0 also fills the per-step scalar table sc.
// ---------------------------------------------------------------------------
__global__ __launch_bounds__(256) void lminit_kernel(
    const float* __restrict__ wp,
    const float* __restrict__ alphap, const float* __restrict__ beltp,
    const float* __restrict__ lrap,  const float* __restrict__ lrbp,
    const float* __restrict__ Rpart, const float* __restrict__ Cpart0,
    float* __restrict__ Lm, float* __restrict__ cc, float* __restrict__ sc)
{
    const int bid = blockIdx.x;
    const int t   = threadIdx.x;
    if (bid == 0 && t < NSTEPS) {
        sc[t]          = alphap[0] * powf(lrap[0], (float)t);
        sc[NSTEPS + t] = beltp[0]  * powf(lrbp[0], (float)t);
    }
    const int b   = bid >> 2;
    const int i   = ((bid & 3) << 8) + t;
    float R0 = 0.f, C0 = 0.f;
#pragma unroll
    for (int k = 0; k < 16; ++k) {
        R0 += Rpart[((size_t)(b * 16 + k)) * L + i];
        C0 += Cpart0[((size_t)(b * 16 + k)) * L + i];
    }
    float rowv = 0.5f * (R0 + C0) - 1.0f;
    float rl = fmaxf(rowv, 0.f);
    float lm = wp[0] * rl;
    Lm[b * L + i] = lm;
    float sg = (rowv > 0.f) ? 1.f : ((rowv < 0.f) ? -1.f : 0.f);
    cc[b * L + i] = lm * sg;
}

__device__ __forceinline__ float step_elem(float a, float u, float rho,
                                           float ci, float cj, float at) {
    float g = u - ci - cj;
    float v = a * (1.f + at * g);
    v = fmaxf(fabsf(v) - rho * at, 0.f);
    return fminf(v, 1.f);
}

// ---------------------------------------------------------------------------
// update: 512 blocks x 512 threads = (batch b, 8-row slab); wave w (of 8)
// owns row slab*8+w; lane l owns cols k*256+l*4. XCD swizzle: bid%8 =
// row-chunk so every step the SAME XCD L2 serves a block's ah/us/rho rows.
// Mapping identical across all 15 dispatches + init. Proven 277us body —
// unchanged. (Only steps 0..14 run this; step 15 is fused into updfinal.)
// ---------------------------------------------------------------------------
__global__ __launch_bounds__(512) void update_kernel(
    const float* __restrict__ rho, const float* __restrict__ sc,
    float* __restrict__ ah, const float* __restrict__ us,
    const float* __restrict__ cc,
    float* __restrict__ R, float* __restrict__ Cpart, int p)
{
    __shared__ float cp[8][1024];
    const int bid   = blockIdx.x;
    const int chunk = bid & 7;            // row-chunk -> XCD (round-robin)
    const int rest  = bid >> 3;           // 0..63
    const int b     = rest >> 4;          // 0..3
    const int slab  = (chunk << 4) | (rest & 15);   // 0..127
    const int t    = threadIdx.x;
    const int w    = t >> 6;
    const int l    = t & 63;
    const int row  = (slab << 3) + w;
    const size_t rowoff = (size_t)b * L * L + (size_t)row * L;
    const float at = sc[p];
    const float* ccb = cc + b * L;

    float4 cj[4];
#pragma unroll
    for (int k = 0; k < 4; ++k)
        cj[k] = *(const float4*)(ccb + k * 256 + l * 4);
    const float ci = ccb[row];

    float4 a4[4], u4[4], h4[4];
#pragma unroll
    for (int k = 0; k < 4; ++k) {
        const size_t off = rowoff + k * 256 + l * 4;
        a4[k] = *(const float4*)(ah + off);
        u4[k] = *(const float4*)(us + off);
        h4[k] = *(const float4*)(rho + (size_t)row * L + k * 256 + l * 4);
    }
#pragma unroll
    for (int k = 0; k < 4; ++k) {
        a4[k].x = step_elem(a4[k].x, u4[k].x, h4[k].x, ci, cj[k].x, at);
        a4[k].y = step_elem(a4[k].y, u4[k].y, h4[k].y, ci, cj[k].y, at);
        a4[k].z = step_elem(a4[k].z, u4[k].z, h4[k].z, ci, cj[k].z, at);
        a4[k].w = step_elem(a4[k].w, u4[k].w, h4[k].w, ci, cj[k].w, at);
        *(float4*)(ah + rowoff + k * 256 + l * 4) = a4[k];
    }

    // row sum (full row lives in this wave; single owner -> plain store)
    float rs = 0.f;
#pragma unroll
    for (int k = 0; k < 4; ++k)
        rs += (a4[k].x + a4[k].y) + (a4[k].z + a4[k].w);
    rs += __shfl_xor(rs, 1);  rs += __shfl_xor(rs, 2);  rs += __shfl_xor(rs, 4);
    rs += __shfl_xor(rs, 8);  rs += __shfl_xor(rs, 16); rs += __shfl_xor(rs, 32);
    if (l == 0) R[b * L + row] = rs;

    // column partial: 8 waves -> LDS -> combine -> one float2 store/thread
#pragma unroll
    for (int k = 0; k < 4; ++k)
        *(float4*)&cp[w][k * 256 + l * 4] = a4[k];
    __syncthreads();
    const int c0 = t * 2;
    float2 acc = make_float2(0.f, 0.f);
#pragma unroll
    for (int j = 0; j < 8; ++j) {
        float2 v = *(float2*)&cp[j][c0];
        acc.x += v.x; acc.y += v.y;
    }
    *(float2*)(Cpart + ((size_t)(b * 128 + slab)) * L + c0) = acc;
}

// ---------------------------------------------------------------------------
// lmreduce: 64 blocks x 1024 threads; block (b, 64-col chunk). Wave w (of 16)
// sums partial slabs w*8..w*8+7; LDS combine; wave 0 updates Lm/cc.
// ---------------------------------------------------------------------------
__global__ __launch_bounds__(1024) void lmreduce_kernel(
    const float* __restrict__ sc,
    const float* __restrict__ Cpart, const float* __restrict__ R,
    float* __restrict__ Lm, float* __restrict__ cc, int p)
{
    __shared__ float red[16][64];
    const int bid = blockIdx.x;
    const int b   = bid >> 4;
    const int c0  = (bid & 15) << 6;
    const int t   = threadIdx.x;
    const int w   = t >> 6;
    const int l   = t & 63;
    const int c   = c0 + l;

    const float* base = Cpart + (size_t)b * 128 * L + c;
    float v = 0.f;
#pragma unroll
    for (int k = w * 8; k < w * 8 + 8; ++k)
        v += base[(size_t)k * L];
    red[w][l] = v;
    __syncthreads();

    if (w == 0) {
        float total = 0.f;
#pragma unroll
        for (int j = 0; j < 16; ++j) total += red[j][l];
        float rowv = 0.5f * (R[b * L + c] + total) - 1.0f;
        float rl = fmaxf(rowv, 0.f);
        float lm = Lm[b * L + c] + sc[NSTEPS + p] * rl;
        Lm[b * L + c] = lm;
        float sg = (rowv > 0.f) ? 1.f : ((rowv < 0.f) ? -1.f : 0.f);
        cc[b * L + c] = lm * sg;
    }
}

// ---------------------------------------------------------------------------
// updfinal: step-15 update FUSED with symmetrize-output (verified correct in
// R6-R10). Tile-pair per block: compute step 15 for the (ti,tj) AND (tj,ti)
// tiles (us is symmetric — read once, transpose via LDS; rho/ah are not,
// read direct), combine, write out. ah never written back — saves the
// 16.8MB ah write of update(15) plus final's full ah re-read and one
// dispatch boundary. cc comes from the ordinary lmreduce(14) dispatch —
// no flags, no spins, no agent-scope anything.
// ---------------------------------------------------------------------------
__device__ __forceinline__ void decode_pair(int p, int& ti, int& tj) {
    int t = 0;
    while (p >= NTILE - t) { p -= NTILE - t; ++t; }
    ti = t; tj = t + p;
}

__global__ __launch_bounds__(256) void updfinal_kernel(
    const float* __restrict__ rho, const float* __restrict__ sc,
    const float* __restrict__ ah, const float* __restrict__ us,
    const float* __restrict__ cc, float* __restrict__ out)
{
    __shared__ float la[64][65];
    __shared__ float lb[64][65];
    __shared__ float uu[64][65];
    const int task = blockIdx.x;
    const int b = task / NPAIR;
    int ti, tj; decode_pair(task % NPAIR, ti, tj);
    const int t  = threadIdx.x;
    const int r0 = t >> 4;
    const int c0 = (t & 15) << 2;
    const float at = sc[NSTEPS - 1];
    const float* ccb = cc + b * L;
    const float* ahb = ah  + (size_t)b * L * L;
    const float* usb = us  + (size_t)b * L * L;
    float* ob        = out + (size_t)b * L * L;

    // pass 1: (ti,tj) tile — direct orientation
    {
        float4 cjv = *(const float4*)(ccb + tj * 64 + c0);
        for (int it = 0; it < 4; ++it) {
            int r = r0 + 16 * it;
            int gi = ti * 64 + r;
            size_t off = (size_t)gi * L + tj * 64 + c0;
            float4 av = *(const float4*)(ahb + off);
            float4 uv = *(const float4*)(usb + off);
            float4 hv = *(const float4*)(rho + off);
            float ci = ccb[gi];
            la[r][c0+0] = step_elem(av.x, uv.x, hv.x, ci, cjv.x, at);
            la[r][c0+1] = step_elem(av.y, uv.y, hv.y, ci, cjv.y, at);
            la[r][c0+2] = step_elem(av.z, uv.z, hv.z, ci, cjv.z, at);
            la[r][c0+3] = step_elem(av.w, uv.w, hv.w, ci, cjv.w, at);
            uu[r][c0+0] = uv.x; uu[r][c0+1] = uv.y;
            uu[r][c0+2] = uv.z; uu[r][c0+3] = uv.w;
        }
    }
    __syncthreads();
    // pass 2: (tj,ti) tile — us from transposed LDS (us symmetric)
    if (ti != tj) {
        float4 cjv = *(const float4*)(ccb + ti * 64 + c0);
        for (int it = 0; it < 4; ++it) {
            int r = r0 + 16 * it;
            int gi = tj * 64 + r;
            size_t off = (size_t)gi * L + ti * 64 + c0;
            float4 av = *(const float4*)(ahb + off);
            float4 hv = *(const float4*)(rho + off);
            float ci = ccb[gi];
            lb[r][c0+0] = step_elem(av.x, uu[c0+0][r], hv.x, ci, cjv.x, at);
            lb[r][c0+1] = step_elem(av.y, uu[c0+1][r], hv.y, ci, cjv.y, at);
            lb[r][c0+2] = step_elem(av.z, uu[c0+2][r], hv.z, ci, cjv.z, at);
            lb[r][c0+3] = step_elem(av.w, uu[c0+3][r], hv.w, ci, cjv.w, at);
        }
    }
    __syncthreads();

    for (int it = 0; it < 4; ++it) {
        int r = r0 + 16 * it;
        size_t off = (size_t)(ti * 64 + r) * L + tj * 64 + c0;
        float tb0, tb1, tb2, tb3;
        if (ti == tj) { tb0 = la[c0+0][r]; tb1 = la[c0+1][r]; tb2 = la[c0+2][r]; tb3 = la[c0+3][r]; }
        else          { tb0 = lb[c0+0][r]; tb1 = lb[c0+1][r]; tb2 = lb[c0+2][r]; tb3 = lb[c0+3][r]; }
        *(float4*)(ob + off) = make_float4(0.5f*(la[r][c0+0]+tb0), 0.5f*(la[r][c0+1]+tb1),
                                           0.5f*(la[r][c0+2]+tb2), 0.5f*(la[r][c0+3]+tb3));
    }
    if (ti != tj) {
        for (int it = 0; it < 4; ++it) {
            int r = r0 + 16 * it;
            size_t off = (size_t)(tj * 64 + r) * L + ti * 64 + c0;
            *(float4*)(ob + off) = make_float4(0.5f*(lb[r][c0+0]+la[c0+0][r]),
                                               0.5f*(lb[r][c0+1]+la[c0+1][r]),
                                               0.5f*(lb[r][c0+2]+la[c0+2][r]),
                                               0.5f*(lb[r][c0+3]+la[c0+3][r]));
        }
    }
}

extern "C" void kernel_launch(void* const* d_in, const int* in_sizes, int n_in,
                              void* d_out, int out_size, void* d_ws, size_t ws_size,
                              hipStream_t stream) {
    const float* x     = (const float*)d_in[0];
    const float* M     = (const float*)d_in[1];
    const float* s     = (const float*)d_in[2];
    const float* w     = (const float*)d_in[3];
    const float* rho   = (const float*)d_in[4];
    const float* alpha = (const float*)d_in[5];
    const float* belt  = (const float*)d_in[6];
    const float* lra   = (const float*)d_in[7];
    const float* lrb   = (const float*)d_in[8];
    float* out = (float*)d_out;

    float* ws     = (float*)d_ws;
    float* ah     = ws + AH_OFF;
    float* us     = ws + US_OFF;
    float* Cpart  = ws + CP_OFF;
    float* Rpart  = ws + RP0_OFF;
    float* Cpart0 = ws + CP0_OFF;
    float* R      = ws + R_OFF;
    float* Lm     = ws + LM_OFF;
    float* cc     = ws + CC_OFF;
    float* sc     = ws + SC_OFF;

    init_kernel<<<dim3(1024), dim3(256), 0, stream>>>(x, M, s, ah, us, Rpart, Cpart0);
    lminit_kernel<<<dim3(16), dim3(256), 0, stream>>>(
        w, alpha, belt, lra, lrb, Rpart, Cpart0, Lm, cc, sc);
    for (int p = 0; p < NSTEPS - 1; ++p) {
        update_kernel<<<dim3(512), dim3(512), 0, stream>>>(
            rho, sc, ah, us, cc, R, Cpart, p);
        lmreduce_kernel<<<dim3(64), dim3(1024), 0, stream>>>(
            sc, Cpart, R, Lm, cc, p);
    }
    // step 15 fused with symmetrize-output: reads cc from lmreduce(14)
    updfinal_kernel<<<dim3(B * NPAIR), dim3(256), 0, stream>>>(
        rho, sc, ah, us, cc, out);
}